// Round 13
// baseline (364.898 us; speedup 1.0000x reference)
//
#include <hip/hip_runtime.h>

#define N_NODES 50000
#define N_EDGES 200000
#define DE 32
#define N_FRAG 10000
#define N_GRAPH 2000
#define BN_SLOTS 32
#define KSTR 296   // LDS stride (fp16 elems) for the 64-row A/h1 plane
#define NSCAN ((N_NODES + 255) / 256)   // 196 scan blocks

typedef _Float16 f16x8 __attribute__((ext_vector_type(8)));
typedef _Float16 f16x4 __attribute__((ext_vector_type(4)));
typedef __attribute__((ext_vector_type(4))) float f32x4;

__device__ __forceinline__ float4 ld4(const float* p) { return *(const float4*)p; }
__device__ __forceinline__ float4 ld4(const _Float16* p) {
    f16x4 h = *(const f16x4*)p;
    float4 v; v.x = (float)h[0]; v.y = (float)h[1]; v.z = (float)h[2]; v.w = (float)h[3];
    return v;
}
__device__ __forceinline__ void st4h(_Float16* p, float4 v) {
    f16x4 h = {(_Float16)v.x, (_Float16)v.y, (_Float16)v.z, (_Float16)v.w};
    *(f16x4*)p = h;
}

// ---------------------------------------------------------------------------
// prep1 mega-kernel: 5 independent jobs in one dispatch (block-range split):
//   job0 bs16_all (weight swizzle), job1 count_deg, job2 segptr (frag+graph),
//   job3 relu16 (Y0 = fp16(relu(x))), job4 zero bnslots.
struct PrepArgs {
    const float* W[6];
    _Float16* BS[6];
    int base[7];            // cumulative bs16 element counts
    int nb_bs;
    const int* ei;
    int* deg;
    int nb_deg;
    const int* fb; const int* gb;
    int* frag_ptr; int* graph_ptr;
    int nb_seg;
    const float* x;
    _Float16* y0;
    int nb_relu;
    float* bnslots;
};

__global__ __launch_bounds__(256)
void prep1_kernel(PrepArgs a) {
    int b = blockIdx.x;
    const int t = threadIdx.x;
    if (b < a.nb_bs) {
        int id = b * 256 + t;
        if (id < a.base[6]) {
            int seg = 0;
#pragma unroll
            for (int i = 1; i < 6; ++i) seg += (id >= a.base[i]);
            int lid = id - a.base[seg];
            int j  = lid & 7;
            int l  = (lid >> 3) & 63;
            int cg = (lid >> 9) & 15;
            int kt = lid >> 13;
            int col = cg * 16 + (l & 15);
            int k   = kt * 32 + (l >> 4) * 8 + j;
            a.BS[seg][lid] = (_Float16)a.W[seg][(size_t)k * 256 + col];
        }
        return;
    }
    b -= a.nb_bs;
    if (b < a.nb_deg) {
        int e = b * 256 + t;
        if (e < N_EDGES) atomicAdd(&a.deg[a.ei[N_EDGES + e]], 1);
        return;
    }
    b -= a.nb_deg;
    if (b < a.nb_seg) {
        int id = b * 256 + t;
        const int* batch;
        int* ptr;
        int s;
        if (id <= N_FRAG) { batch = a.fb; ptr = a.frag_ptr; s = id; }
        else if (id <= N_FRAG + 1 + N_GRAPH) { batch = a.gb; ptr = a.graph_ptr; s = id - (N_FRAG + 1); }
        else return;
        int lo = 0, hi = N_NODES;
        while (lo < hi) {
            int mid = (lo + hi) >> 1;
            if (batch[mid] < s) lo = mid + 1; else hi = mid;
        }
        ptr[s] = lo;
        return;
    }
    b -= a.nb_seg;
    if (b < a.nb_relu) {
        size_t i = ((size_t)b * 256 + t) * 4;   // relu16: N*128 elements
        if (i < (size_t)N_NODES * 128) {
            float4 v = ld4(a.x + i);
            f16x4 o = {(_Float16)fmaxf(v.x, 0.f), (_Float16)fmaxf(v.y, 0.f),
                       (_Float16)fmaxf(v.z, 0.f), (_Float16)fmaxf(v.w, 0.f)};
            *(f16x4*)(a.y0 + i) = o;
        }
        return;
    }
    b -= a.nb_relu;
    int zi = b * 256 + t;                       // zero bnslots
    if (zi < 3 * BN_SLOTS * 512) a.bnslots[zi] = 0.f;
}

// ---------------------------------------------------------------------------
// Single-dispatch CSR build: decoupled-lookback prefix scan over deg ->
// row_ptr, hand-rolled grid barrier (196 blocks, trivially co-resident:
// 50k threads vs 524k capacity), then grid-strided fill phase.
// Replaces block_sum + top_scan + final_scan + fill_csr (4 dispatches).
__global__ __launch_bounds__(256)
void scan_fill_kernel(const int* __restrict__ deg, const int* __restrict__ ei,
                      int* __restrict__ row_ptr, int* __restrict__ fill,
                      int* __restrict__ csr_src, int* __restrict__ csr_eid,
                      int* __restrict__ agg, int* __restrict__ incl,
                      int* __restrict__ state, int* __restrict__ done) {
    __shared__ int s[256];
    __shared__ int sexcl;
    const int b = blockIdx.x, t = threadIdx.x;
    const int i = b * 256 + t;
    int v = (i < N_NODES) ? deg[i] : 0;
    s[t] = v;
    __syncthreads();
    for (int o = 1; o < 256; o <<= 1) {
        int x = s[t];
        int a = (t >= o) ? s[t - o] : 0;
        __syncthreads();
        s[t] = x + a;
        __syncthreads();
    }
    int total = s[255];
    if (t == 0) {
        if (b == 0) {
            incl[0] = total;
            __threadfence();
            atomicExch(&state[0], 2);
            sexcl = 0;
        } else {
            agg[b] = total;
            __threadfence();
            atomicExch(&state[b], 1);
            int excl = 0;
            int p = b - 1;
            while (p >= 0) {
                int st;
                do { st = atomicAdd(&state[p], 0); } while (st == 0);
                if (st == 2) { excl += atomicAdd(&incl[p], 0); break; }
                excl += atomicAdd(&agg[p], 0);
                --p;
            }
            incl[b] = excl + total;
            __threadfence();
            atomicExch(&state[b], 2);
            sexcl = excl;
        }
    }
    __syncthreads();
    int base = sexcl;
    if (i < N_NODES) row_ptr[i] = base + s[t] - v;
    if (i == N_NODES - 1) row_ptr[N_NODES] = base + s[t];
    // ---- grid barrier ----
    __threadfence();
    __syncthreads();
    if (t == 0) {
        atomicAdd(done, 1);
        while (atomicAdd(done, 0) < (int)gridDim.x) {}
    }
    __syncthreads();
    __threadfence();
    // ---- fill CSR ----
    for (int e = b * 256 + t; e < N_EDGES; e += gridDim.x * 256) {
        int dst = ei[N_EDGES + e];
        int pos = row_ptr[dst] + atomicAdd(&fill[dst], 1);
        csr_src[pos] = ei[e];
        csr_eid[pos] = e;
    }
}

// ---------------------------------------------------------------------------
// Fused gather + MLP, 64-row M-tile, 512 threads / 8 waves.
// BNIN layers: per-block prologue computes BN scale/shift of the PREVIOUS
// layer from its L2-hot stat slots (bit-identical fp32 reduction to the old
// bnfin kernel); self term uses fp32 sc/sh from LDS; the neighbor gather
// applies relu(BN(h[src])) per edge in PACKED fp16 (pk_fma/pk_max) — the
// bnfin_relu16 dispatch and its 51MB Y round-trip are deleted.
// Layer 0 (!BNIN): neighbors from pre-relu'd Y0; inline edge aggregation
// (fp32, CSR order) writes agg_e for layers 1/2.
template <bool BNIN, typename T, int NC>   // DIN = NC*32, K1 = DIN+32
__global__ __launch_bounds__(512, 4)
void fused_mlp_kernel(const T* __restrict__ X, const _Float16* __restrict__ Yg,
                      const int* __restrict__ row_ptr, const int* __restrict__ csr_src,
                      const int* __restrict__ csr_eid, const float* __restrict__ ea,
                      float* __restrict__ agg_e,
                      const float* __restrict__ prev_slots,
                      const float* __restrict__ prev_g, const float* __restrict__ prev_beta,
                      const _Float16* __restrict__ B1, const float* __restrict__ bias1,
                      const _Float16* __restrict__ B2, const float* __restrict__ bias2,
                      _Float16* __restrict__ C, float* __restrict__ bnslot) {
    constexpr int DIN  = NC * 32;
    constexpr int K1   = DIN + 32;
    constexpr int NKT1 = K1 / 32;
    constexpr int CPT  = DIN / 8;        // cols per stage-thread
    constexpr int NV   = CPT / 8;        // f16x8 chunks per stage-thread
    __shared__ __align__(16) _Float16 sBuf[64 * KSTR];   // A tile, h1, then C
    __shared__ float ssc[256], ssh[256];
    const int t = threadIdx.x;
    const int l = t & 63;
    const int w = t >> 6;                // 8 waves
    const int lr = l & 15;
    const int lq = l >> 4;
    const int row0 = blockIdx.x << 6;    // 64 rows/block
    const int cb = w << 5;               // 32-col slab per wave

    // ---- BN prologue (BNIN): prev-layer scale/shift from stat slots ----
    if (BNIN) {
        if (t < 256) {
            float s = 0.f, q = 0.f;
            for (int k = 0; k < BN_SLOTS; ++k) {
                s += prev_slots[(size_t)k * 512 + t];
                q += prev_slots[(size_t)k * 512 + 256 + t];
            }
            float mu = s * (1.0f / N_NODES);
            float var = q * (1.0f / N_NODES) - mu * mu;
            float rstd = rsqrtf(var + 1e-5f);
            float sc = prev_g[t] * rstd;
            ssc[t] = sc;
            ssh[t] = prev_beta[t] - mu * sc;
        }
        __syncthreads();
    }

    // ---- stage: gather-aggregate into LDS (8 threads/row, 64 rows) ----
    {
        const int r = t >> 3, j = t & 7;
        const int jc = j << 3;           // lane's 8-col offset within a chunk
        const int gr = row0 + r;
        const _Float16* nbp = BNIN ? (const _Float16*)(const void*)X : Yg;
        f16x8 sc16[NV], sh16[NV];
        if (BNIN) {
#pragma unroll
            for (int c = 0; c < NV; ++c)
#pragma unroll
                for (int k = 0; k < 8; ++k) {
                    sc16[c][k] = (_Float16)ssc[c * 64 + jc + k];
                    sh16[c][k] = (_Float16)ssh[c * 64 + jc + k];
                }
        }
        if (gr < N_NODES) {
            f16x8 acc16[NV];
#pragma unroll
            for (int c = 0; c < NV; ++c) acc16[c] = (f16x8){0, 0, 0, 0, 0, 0, 0, 0};
            float4 eacc = {0.f, 0.f, 0.f, 0.f};
            const int beg = row_ptr[gr], end = row_ptr[gr + 1];
            for (int e = beg; e < end; ++e) {
                const _Float16* sp = nbp + (size_t)csr_src[e] * DIN + jc;
#pragma unroll
                for (int c = 0; c < NV; ++c) {
                    f16x8 v = *(const f16x8*)(sp + c * 64);
                    if (BNIN) {
                        f16x8 yy = v * sc16[c] + sh16[c];
#pragma unroll
                        for (int k = 0; k < 8; ++k)
                            yy[k] = (yy[k] > (_Float16)0.f) ? yy[k] : (_Float16)0.f;
                        acc16[c] += yy;
                    } else {
                        acc16[c] += v;
                    }
                }
                if (!BNIN) {
                    float4 ev = *(const float4*)(ea + (size_t)csr_eid[e] * DE + (j << 2));
                    eacc.x += fmaxf(ev.x, 0.f);
                    eacc.y += fmaxf(ev.y, 0.f);
                    eacc.z += fmaxf(ev.z, 0.f);
                    eacc.w += fmaxf(ev.w, 0.f);
                }
            }
            // self term (BN if BNIN, no relu) + fp16 neighbor sum
            const T* xp = X + (size_t)gr * DIN + jc;
#pragma unroll
            for (int c = 0; c < NV; ++c) {
                float4 v0f = ld4(xp + c * 64);
                float4 v1f = ld4(xp + c * 64 + 4);
                if (BNIN) {
                    float4 sa = *(const float4*)(ssc + c * 64 + jc);
                    float4 sb = *(const float4*)(ssc + c * 64 + jc + 4);
                    float4 ta = *(const float4*)(ssh + c * 64 + jc);
                    float4 tb = *(const float4*)(ssh + c * 64 + jc + 4);
                    v0f.x = fmaf(v0f.x, sa.x, ta.x);
                    v0f.y = fmaf(v0f.y, sa.y, ta.y);
                    v0f.z = fmaf(v0f.z, sa.z, ta.z);
                    v0f.w = fmaf(v0f.w, sa.w, ta.w);
                    v1f.x = fmaf(v1f.x, sb.x, tb.x);
                    v1f.y = fmaf(v1f.y, sb.y, tb.y);
                    v1f.z = fmaf(v1f.z, sb.z, tb.z);
                    v1f.w = fmaf(v1f.w, sb.w, tb.w);
                }
                f16x8 o;
                o[0] = (_Float16)(v0f.x + (float)acc16[c][0]);
                o[1] = (_Float16)(v0f.y + (float)acc16[c][1]);
                o[2] = (_Float16)(v0f.z + (float)acc16[c][2]);
                o[3] = (_Float16)(v0f.w + (float)acc16[c][3]);
                o[4] = (_Float16)(v1f.x + (float)acc16[c][4]);
                o[5] = (_Float16)(v1f.y + (float)acc16[c][5]);
                o[6] = (_Float16)(v1f.z + (float)acc16[c][6]);
                o[7] = (_Float16)(v1f.w + (float)acc16[c][7]);
                *(f16x8*)&sBuf[r * KSTR + c * 64 + jc] = o;
            }
            if (!BNIN) {
                *(float4*)(agg_e + (size_t)gr * DE + (j << 2)) = eacc;  // for l1/l2
                st4h(&sBuf[r * KSTR + DIN + (j << 2)], eacc);
            } else {
                float4 ev = *(const float4*)(agg_e + (size_t)gr * DE + (j << 2));
                st4h(&sBuf[r * KSTR + DIN + (j << 2)], ev);
            }
        } else {
            f16x8 z8 = {0, 0, 0, 0, 0, 0, 0, 0};
#pragma unroll
            for (int c = 0; c < NV; ++c)
                *(f16x8*)&sBuf[r * KSTR + c * 64 + jc] = z8;
            f16x4 z4 = {0, 0, 0, 0};
            *(f16x4*)&sBuf[r * KSTR + DIN + (j << 2)] = z4;
        }
    }
    __syncthreads();

    // ---- phase 1: A @ W1 (barrier-free) ----
    f32x4 acc1[4][2];
#pragma unroll
    for (int mt = 0; mt < 4; ++mt)
#pragma unroll
        for (int nt = 0; nt < 2; ++nt) acc1[mt][nt] = (f32x4){0.f, 0.f, 0.f, 0.f};
#pragma unroll
    for (int kt = 0; kt < NKT1; ++kt) {
        f16x8 af[4], bf[2];
#pragma unroll
        for (int mt = 0; mt < 4; ++mt)
            af[mt] = *(const f16x8*)&sBuf[(mt * 16 + lr) * KSTR + (kt << 5) + (lq << 3)];
        const size_t bb = ((size_t)(kt * 16 + (w << 1))) * 512 + (l << 3);
#pragma unroll
        for (int nt = 0; nt < 2; ++nt)
            bf[nt] = *(const f16x8*)(B1 + bb + nt * 512);
#pragma unroll
        for (int mt = 0; mt < 4; ++mt)
#pragma unroll
            for (int nt = 0; nt < 2; ++nt)
                acc1[mt][nt] = __builtin_amdgcn_mfma_f32_16x16x32_f16(
                    af[mt], bf[nt], acc1[mt][nt], 0, 0, 0);
    }
    __syncthreads();   // A tile dead; reuse plane for h1

    // ---- epilogue 1: relu(h1) -> LDS fp16 ----
#pragma unroll
    for (int nt = 0; nt < 2; ++nt) {
        int col = cb + nt * 16 + lr;
        float bv = bias1[col];
#pragma unroll
        for (int mt = 0; mt < 4; ++mt)
#pragma unroll
            for (int i = 0; i < 4; ++i) {
                int rr = mt * 16 + lq * 4 + i;
                sBuf[rr * KSTR + col] = (_Float16)fmaxf(acc1[mt][nt][i] + bv, 0.f);
            }
    }
    __syncthreads();

    // ---- phase 2: h1 @ W2 (barrier-free) ----
    f32x4 acc2[4][2];
#pragma unroll
    for (int mt = 0; mt < 4; ++mt)
#pragma unroll
        for (int nt = 0; nt < 2; ++nt) acc2[mt][nt] = (f32x4){0.f, 0.f, 0.f, 0.f};
#pragma unroll
    for (int kt = 0; kt < 8; ++kt) {
        f16x8 af[4], bf[2];
#pragma unroll
        for (int mt = 0; mt < 4; ++mt)
            af[mt] = *(const f16x8*)&sBuf[(mt * 16 + lr) * KSTR + (kt << 5) + (lq << 3)];
        const size_t bb = ((size_t)(kt * 16 + (w << 1))) * 512 + (l << 3);
#pragma unroll
        for (int nt = 0; nt < 2; ++nt)
            bf[nt] = *(const f16x8*)(B2 + bb + nt * 512);
#pragma unroll
        for (int mt = 0; mt < 4; ++mt)
#pragma unroll
            for (int nt = 0; nt < 2; ++nt)
                acc2[mt][nt] = __builtin_amdgcn_mfma_f32_16x16x32_f16(
                    af[mt], bf[nt], acc2[mt][nt], 0, 0, 0);
    }
    __syncthreads();   // h1 reads done; reuse plane for C staging

    // ---- epilogue 2: bias + relu -> LDS fp16 + BN stats ----
    float* slot = bnslot + (size_t)(blockIdx.x & (BN_SLOTS - 1)) * 512;
#pragma unroll
    for (int nt = 0; nt < 2; ++nt) {
        int col = cb + nt * 16 + lr;
        float bv = bias2[col];
        float s = 0.f, qq = 0.f;
#pragma unroll
        for (int mt = 0; mt < 4; ++mt)
#pragma unroll
            for (int i = 0; i < 4; ++i) {
                int rr = mt * 16 + lq * 4 + i;
                float o = fmaxf(acc2[mt][nt][i] + bv, 0.f);
                sBuf[rr * KSTR + col] = (_Float16)o;
                if (row0 + rr < N_NODES) { s += o; qq += o * o; }
            }
        s += __shfl_xor(s, 16); s += __shfl_xor(s, 32);
        qq += __shfl_xor(qq, 16); qq += __shfl_xor(qq, 32);
        if (lq == 0) {
            atomicAdd(&slot[col], s);
            atomicAdd(&slot[256 + col], qq);
        }
    }
    __syncthreads();

    // ---- coalesced C write: f16x8 per thread, 512B contiguous per row ----
#pragma unroll
    for (int k = 0; k < 4; ++k) {
        int rr  = (t >> 5) + k * 16;
        int col = (t & 31) * 8;
        int row = row0 + rr;
        if (row < N_NODES) {
            f16x8 v = *(const f16x8*)&sBuf[rr * KSTR + col];
            *(f16x8*)(C + (size_t)row * 256 + col) = v;
        }
    }
}

// ---------------------------------------------------------------------------
// Both segmented sqrt-pools (frag + graph) in ONE dispatch, with layer-2
// BN finalize computed per-block in a prologue (L2-hot slots).
__global__ __launch_bounds__(256)
void pool_both_kernel(const _Float16* __restrict__ h,
                      const int* __restrict__ frag_ptr, const int* __restrict__ graph_ptr,
                      const float* __restrict__ slots,
                      const float* __restrict__ g2, const float* __restrict__ beta2,
                      float* __restrict__ out) {
    __shared__ float ssc[256], ssh[256];
    const int t = threadIdx.x;
    {
        float s = 0.f, q = 0.f;
        for (int k = 0; k < BN_SLOTS; ++k) {
            s += slots[(size_t)k * 512 + t];
            q += slots[(size_t)k * 512 + 256 + t];
        }
        float mu = s * (1.0f / N_NODES);
        float var = q * (1.0f / N_NODES) - mu * mu;
        float rstd = rsqrtf(var + 1e-5f);
        float sc = g2[t] * rstd;
        ssc[t] = sc;
        ssh[t] = beta2[t] - mu * sc;
    }
    __syncthreads();
    const int NFB = (N_FRAG + 3) / 4;   // frag blocks first, then graph
    int b = blockIdx.x;
    const int* ptr; float* o; int nseg; int sb;
    if (b < NFB) { ptr = frag_ptr; o = out; nseg = N_FRAG; sb = b * 4; }
    else { ptr = graph_ptr; o = out + (size_t)N_FRAG * 256; nseg = N_GRAPH; sb = (b - NFB) * 4; }
    int g = t >> 6;
    int j = t & 63;
    int s = sb + g;
    if (s >= nseg) return;
    int beg = ptr[s], end = ptr[s + 1];
    int col = j << 2;
    float4 sc = *(const float4*)(ssc + col);
    float4 sh = *(const float4*)(ssh + col);
    float4 acc = {0.f, 0.f, 0.f, 0.f};
    for (int i = beg; i < end; ++i) {
        float4 v = ld4(h + (size_t)i * 256 + col);
        acc.x += fmaf(v.x, sc.x, sh.x);
        acc.y += fmaf(v.y, sc.y, sh.y);
        acc.z += fmaf(v.z, sc.z, sh.z);
        acc.w += fmaf(v.w, sc.w, sh.w);
    }
    float w = rsqrtf(fmaxf((float)(end - beg), 1.0f));
    float4 ov = {acc.x * w, acc.y * w, acc.z * w, acc.w * w};
    *(float4*)(o + (size_t)s * 256 + col) = ov;
}

// ---------------------------------------------------------------------------
extern "C" void kernel_launch(void* const* d_in, const int* in_sizes, int n_in,
                              void* d_out, int out_size, void* d_ws, size_t ws_size,
                              hipStream_t stream) {
    const float* x  = (const float*)d_in[0];
    const float* ea = (const float*)d_in[1];
    const int*   ei = (const int*)d_in[2];
    const int*   fb = (const int*)d_in[3];
    const int*   gb = (const int*)d_in[4];
    const float* W1[3]   = {(const float*)d_in[5],  (const float*)d_in[11], (const float*)d_in[17]};
    const float* B1[3]   = {(const float*)d_in[6],  (const float*)d_in[12], (const float*)d_in[18]};
    const float* W2[3]   = {(const float*)d_in[7],  (const float*)d_in[13], (const float*)d_in[19]};
    const float* B2[3]   = {(const float*)d_in[8],  (const float*)d_in[14], (const float*)d_in[20]};
    const float* G[3]    = {(const float*)d_in[9],  (const float*)d_in[15], (const float*)d_in[21]};
    const float* BETA[3] = {(const float*)d_in[10], (const float*)d_in[16], (const float*)d_in[22]};

    const int FIN[3] = {160, 288, 288};

    float* ws = (float*)d_ws;
    size_t off = 0;
    _Float16* bufA = (_Float16*)(ws + off); off += (size_t)N_NODES * 128;  // N x 256 fp16
    _Float16* bufB = (_Float16*)(ws + off); off += (size_t)N_NODES * 128;
    _Float16* ybuf = (_Float16*)(ws + off); off += (size_t)N_NODES * 128;  // Y0 (layer 0 only)
    float* agg_e = ws + off; off += (size_t)N_NODES * DE;
    float* bnslots = ws + off; off += (size_t)3 * BN_SLOTS * 512;
    _Float16* w1f[3]; _Float16* w2f[3];
    {
        _Float16* sw = (_Float16*)(ws + off);
        _Float16* sw0 = sw;
        for (int l = 0; l < 3; ++l) { w1f[l] = sw; sw += 256 * FIN[l]; }
        for (int l = 0; l < 3; ++l) { w2f[l] = sw; sw += 256 * 256; }
        off += (size_t)(sw - sw0 + 1) / 2;
    }
    int* iw      = (int*)(ws + off);
    int* deg      = iw;                    iw += N_NODES;
    int* fill     = iw;                    iw += N_NODES;
    int* sc_agg   = iw;                    iw += NSCAN;
    int* sc_incl  = iw;                    iw += NSCAN;
    int* sc_state = iw;                    iw += NSCAN;
    int* sc_done  = iw;                    iw += 1;
    int* row_ptr  = iw;                    iw += N_NODES + 1;
    int* csr_src  = iw;                    iw += N_EDGES;
    int* csr_eid  = iw;                    iw += N_EDGES;
    int* frag_ptr = iw;                    iw += N_FRAG + 1;
    int* graph_ptr = iw;                   iw += N_GRAPH + 1;

    // zero deg, fill, and scan aux in one memset (contiguous)
    hipMemsetAsync(deg, 0, (size_t)(2 * N_NODES + 3 * NSCAN + 1) * sizeof(int), stream);

    // prep1: weight swizzle + deg count + segptrs + Y0 relu + bnslots zero
    {
        PrepArgs a;
        a.W[0] = W1[0]; a.W[1] = W1[1]; a.W[2] = W1[2];
        a.W[3] = W2[0]; a.W[4] = W2[1]; a.W[5] = W2[2];
        a.BS[0] = w1f[0]; a.BS[1] = w1f[1]; a.BS[2] = w1f[2];
        a.BS[3] = w2f[0]; a.BS[4] = w2f[1]; a.BS[5] = w2f[2];
        int Ks[6] = {FIN[0], FIN[1], FIN[2], 256, 256, 256};
        int cum = 0;
        for (int i = 0; i < 6; ++i) { a.base[i] = cum; cum += Ks[i] * 256; }
        a.base[6] = cum;
        a.nb_bs  = (cum + 255) / 256;
        a.ei = ei; a.deg = deg;
        a.nb_deg = (N_EDGES + 255) / 256;
        a.fb = fb; a.gb = gb; a.frag_ptr = frag_ptr; a.graph_ptr = graph_ptr;
        a.nb_seg = (N_FRAG + N_GRAPH + 2 + 255) / 256;
        a.x = x; a.y0 = ybuf;
        a.nb_relu = (N_NODES * 128 / 4 + 255) / 256;
        a.bnslots = bnslots;
        int nb_zero = (3 * BN_SLOTS * 512 + 255) / 256;
        prep1_kernel<<<a.nb_bs + a.nb_deg + a.nb_seg + a.nb_relu + nb_zero,
                       256, 0, stream>>>(a);
    }

    // single-dispatch CSR build (scan + grid barrier + fill)
    scan_fill_kernel<<<NSCAN, 256, 0, stream>>>(
        deg, ei, row_ptr, fill, csr_src, csr_eid,
        sc_agg, sc_incl, sc_state, sc_done);

    const int nblk_mlp = (N_NODES + 63) / 64;    // 782 blocks, 64 rows each
    // layer 0: inline edge aggregation (writes agg_e), self = x (fp32)
    fused_mlp_kernel<false, float, 4><<<nblk_mlp, 512, 0, stream>>>(
        x, ybuf, row_ptr, csr_src, csr_eid, ea, agg_e,
        nullptr, nullptr, nullptr,
        w1f[0], B1[0], w2f[0], B2[0], bufA, bnslots);

    // layer 1: BN of layer-0 computed in-kernel from slots
    fused_mlp_kernel<true, _Float16, 8><<<nblk_mlp, 512, 0, stream>>>(
        bufA, nullptr, row_ptr, csr_src, nullptr, nullptr, agg_e,
        bnslots, G[0], BETA[0],
        w1f[1], B1[1], w2f[1], B2[1], bufB, bnslots + (size_t)1 * BN_SLOTS * 512);

    // layer 2
    fused_mlp_kernel<true, _Float16, 8><<<nblk_mlp, 512, 0, stream>>>(
        bufB, nullptr, row_ptr, csr_src, nullptr, nullptr, agg_e,
        bnslots + (size_t)1 * BN_SLOTS * 512, G[1], BETA[1],
        w1f[2], B1[2], w2f[2], B2[2], bufA, bnslots + (size_t)2 * BN_SLOTS * 512);

    // both pools, with layer-2 BN finalize inline (per-block prologue)
    const int NFB = (N_FRAG + 3) / 4, NGB = (N_GRAPH + 3) / 4;
    pool_both_kernel<<<NFB + NGB, 256, 0, stream>>>(
        bufA, frag_ptr, graph_ptr, bnslots + (size_t)2 * BN_SLOTS * 512,
        G[2], BETA[2], (float*)d_out);
}